// Round 10
// baseline (126.700 us; speedup 1.0000x reference)
//
#include <hip/hip_runtime.h>
#include <hip/hip_bf16.h>

typedef __bf16 bf16x8 __attribute__((ext_vector_type(8)));
typedef float f32x4 __attribute__((ext_vector_type(4)));
typedef float f32x16 __attribute__((ext_vector_type(16)));
typedef unsigned int uint2v __attribute__((ext_vector_type(2)));

#define MFMA16 __builtin_amdgcn_mfma_f32_16x16x32_bf16
#define MFMA32 __builtin_amdgcn_mfma_f32_32x32x16_bf16

__device__ __forceinline__ unsigned short f2b(float f) {
  unsigned int u = __float_as_uint(f);
  u += 0x7FFFu + ((u >> 16) & 1u);
  return (unsigned short)(u >> 16);
}

__device__ __forceinline__ float b2f(unsigned short s) {
  return __uint_as_float(((unsigned)s) << 16);
}

union U128 {
  uint4 u;
  unsigned short s[8];
  bf16x8 b;
};

union BPack {
  __hip_bfloat162 h2;
  unsigned u;
};

__device__ __forceinline__ unsigned packbf(float a, float b) {
  BPack p;
  p.h2 = __float22bfloat162_rn(make_float2(a, b));
  return p.u;
}

// ---------------- projection via MFMA ----------------
// grid 512 = (b = blk&7, n0 = 64-tile). block 256 (4 waves).
// Y[96 pad][4096] = W[96x64] X[64x4096] per batch, bf16 MFMA 16x16x32.
// wq rows pre-scaled by log2(e) so attention uses native exp2.
// h stored BLOCKED: h_blk[b][n>>3][c][n&7].
// R11: packed stores (f/g one 8 B store; h bounced via LDS, 2x16 B stores).
__global__ __launch_bounds__(256, 2) void proj_kernel(
    const float* __restrict__ x, const float* __restrict__ wq,
    const float* __restrict__ wk, const float* __restrict__ wv_w,
    unsigned short* __restrict__ f_t, unsigned short* __restrict__ g_t,
    unsigned short* __restrict__ h_out) {
  __shared__ unsigned short xT[64 * 64];
  __shared__ unsigned short wT[96 * 72];
  __shared__ unsigned short hT[64 * 72];  // [c][n], pad 72 (16B-aligned rows)

  const int tid = (int)threadIdx.x;
  const int wvp = tid >> 6;
  const int lane = tid & 63;
  const int b = (int)blockIdx.x & 7;
  const int n0 = ((int)blockIdx.x >> 3) << 6;

  // ---- stage xT: thread loads 16 c's for n=lane, packs, swizzled write ----
  {
    const float* xb = x + ((size_t)b << 18) + n0 + lane;
    const int c0 = wvp * 16;
    float xv[16];
#pragma unroll
    for (int cc = 0; cc < 16; ++cc) xv[cc] = xb[(size_t)(c0 + cc) << 12];
#pragma unroll
    for (int p = 0; p < 4; ++p) {
      const int c = c0 + 4 * p;
      uint2 d;
      d.x = packbf(xv[4 * p + 0], xv[4 * p + 1]);
      d.y = packbf(xv[4 * p + 2], xv[4 * p + 3]);
      const int g = c >> 3;
      const int idx = lane * 64 + (((g ^ (lane & 7)) << 3) | (((c >> 2) & 1) << 2));
      *(uint2*)&xT[idx] = d;
    }
  }
  // ---- stage wT (80 rows of 64, bf16); wq scaled by log2(e) ----
#pragma unroll
  for (int i = 0; i < 20; ++i) {
    const int idx = i * 256 + tid;
    const float wval = (idx < 512) ? wq[idx] * 1.44269504f
                     : (idx < 1024) ? wk[idx - 512]
                                    : wv_w[idx - 1024];
    wT[(idx >> 6) * 72 + (idx & 63)] = f2b(wval);
  }
  __syncthreads();

  // ---- compute ----
  const int t = lane & 15, q = lane >> 4;
  const int nloc = wvp * 16 + t;
  U128 Bf[2];
#pragma unroll
  for (int kp = 0; kp < 2; ++kp) {
    const int g = kp * 4 + q;
    Bf[kp].u = *(const uint4*)&xT[nloc * 64 + ((g ^ (nloc & 7)) << 3)];
  }
  const int nabs = n0 + nloc;

  // rt = 0: f (r0-7) / g (r8-15): one packed 8 B store per thread.
  {
    f32x4 acc = {0.f, 0.f, 0.f, 0.f};
#pragma unroll
    for (int kp = 0; kp < 2; ++kp) {
      U128 Af;
      Af.u = *(const uint4*)&wT[t * 72 + ((kp * 4 + q) << 3)];
      acc = MFMA16(Af.b, Bf[kp].b, acc, 0, 0, 0);
    }
    uint2 d;
    d.x = packbf(acc[0], acc[1]);
    d.y = packbf(acc[2], acc[3]);
    unsigned short* dst = (q & 2) ? g_t : f_t;
    *(uint2*)&dst[((size_t)((b << 12) + nabs) << 3) + ((q & 1) << 2)] = d;
  }
  // rt = 1..4: h rows -> LDS, transposed packed readback below.
#pragma unroll
  for (int rt = 1; rt < 5; ++rt) {
    f32x4 acc = {0.f, 0.f, 0.f, 0.f};
#pragma unroll
    for (int kp = 0; kp < 2; ++kp) {
      U128 Af;
      Af.u = *(const uint4*)&wT[(rt * 16 + t) * 72 + ((kp * 4 + q) << 3)];
      acc = MFMA16(Af.b, Bf[kp].b, acc, 0, 0, 0);
    }
    const int cbase = (rt - 1) * 16 + 4 * q;
#pragma unroll
    for (int reg = 0; reg < 4; ++reg)
      hT[(cbase + reg) * 72 + nloc] = f2b(acc[reg]);
  }
  __syncthreads();

  // packed h store: thread owns row c = tid&63, n-quarter = tid>>6.
  {
    const int hc = tid & 63;
    const int hw = tid >> 6;
    const uint4 v0 = *(const uint4*)&hT[hc * 72 + hw * 16];
    const uint4 v1 = *(const uint4*)&hT[hc * 72 + hw * 16 + 8];
    const size_t hbase =
        ((size_t)b << 18) + ((size_t)((n0 + hw * 16) >> 3) << 9) + (hc << 3);
    *(uint4*)&h_out[hbase] = v0;
    *(uint4*)&h_out[hbase + 512] = v1;
  }
}

// ---------------- flash attention ------------------------------------------
// R17 = R16 (grid 512, 256 thr, 4 indep waves, m64/ILP2, in-place S pipe)
// + DEPTH-3 register prefetch + 2-PHASE epilogue.
// Register audit (R15 spill calibration: budget = 128 arch + 128 acc/wave):
// acc side: O x4 + S x2 = 96 <= 128. arch side: H 3x4xU128 = 48, F 3x4 = 12,
// G 8, e[] 16, addr/misc ~30 -> ~115 <= 128. Depth-3 means H/F for tile k
// are issued ~3 bodies (~1200+ cy) before use (R12/16 depth was ~1 body).
// Epilogue: Opart restored to [4][32][66] (17 KB; LDS never binding) ->
// 2 stash/drain phases, 5 barriers (was 4 phases / 9 barriers; R14 showed
// the barrier-heavy epilogue costs several us).
__global__ __launch_bounds__(256, 2) void attn_kernel(
    const unsigned short* __restrict__ f_t, const unsigned short* __restrict__ g_t,
    const unsigned short* __restrict__ h, const float* __restrict__ x,
    const float* __restrict__ gamma, float* __restrict__ out) {
  __shared__ unsigned short Opart[4][32][66];  // [wave][m][c], 16.9 KB
  __shared__ float lred[4][64];
  __shared__ float lsum[64];

  const int tid = (int)threadIdx.x;
  const int wave = tid >> 6;
  const int lane = tid & 63;
  const int ml = lane & 31;
  const int hh = lane >> 5;

  const int b = (int)blockIdx.x & 7;
  const int m0 = ((int)blockIdx.x >> 3) << 6;  // m64 tile base

  const unsigned short* fb = f_t + ((size_t)b << 15);
  const unsigned short* hb = h + ((size_t)b << 18);  // blocked layout

  U128 G0, G1;
  G0.u = make_uint4(0u, 0u, 0u, 0u);
  G1.u = make_uint4(0u, 0u, 0u, 0u);
  if (hh == 0) {
    G0.u = *(const uint4*)(g_t + ((size_t)((b << 12) + m0 + ml) << 3));
    G1.u = *(const uint4*)(g_t + ((size_t)((b << 12) + m0 + 32 + ml) << 3));
  }

  f32x16 O00 = {}, O01 = {}, O10 = {}, O11 = {};
  float2 lp0v = make_float2(0.f, 0.f), lp1v = make_float2(0.f, 0.f);
  const f32x16 ZC = {};

  const int nbase = wave << 10;  // n-quarter per wave (1024 n = 32 tiles)

  const unsigned short* fp = fb + ((size_t)(nbase + ml) << 3);
  const unsigned short* hp = hb + ((nbase >> 3) << 9) + (hh << 9) + (ml << 3);

  // fragment slots: 3 H sets + 3 F slots (depth-3 rotation), TWO in-place S
  U128 F_A, F_B, F_C, HaA[4], HaB[4], HaC[4];
  f32x16 S0, S1;

  auto loadH = [&](U128* Hs, const unsigned short* base) {
    Hs[0].u = *(const uint4*)(base);
    Hs[1].u = *(const uint4*)(base + 256);
    Hs[2].u = *(const uint4*)(base + 1024);
    Hs[3].u = *(const uint4*)(base + 1280);
  };

  // prologue: H tiles 0,1,2; F tiles 0,1,2; S = scores(tile 0)
  loadH(HaA, hp);
  loadH(HaB, hp + 2048);
  loadH(HaC, hp + 4096);
  F_A.u = *(const uint4*)(fp);
  F_B.u = *(const uint4*)(fp + 256);
  F_C.u = *(const uint4*)(fp + 512);
  __builtin_amdgcn_s_setprio(1);
  S0 = MFMA32(F_A.b, G0.b, ZC, 0, 0, 0);
  S1 = MFMA32(F_A.b, G1.b, ZC, 0, 0, 0);
  __builtin_amdgcn_s_setprio(0);

  // half: exps consume S (tile k, this G); if produce, S <- scores(k+1)
  // in place; pack + PV into this m-tile's O pair using shared H fragments.
  auto half = [&](f32x16& S, const U128& G, float2& lp, f32x16& Oa, f32x16& Ob,
                  const U128* Hv, const U128& Fn, bool produce) {
    float e[16];
#pragma unroll
    for (int r = 0; r < 16; ++r) e[r] = __builtin_amdgcn_exp2f(S[r]);
    if (produce) {
      __builtin_amdgcn_s_setprio(1);
      S = MFMA32(Fn.b, G.b, ZC, 0, 0, 0);
      __builtin_amdgcn_s_setprio(0);
    }
    lp.x += ((e[0] + e[2]) + (e[4] + e[6])) + ((e[8] + e[10]) + (e[12] + e[14]));
    lp.y += ((e[1] + e[3]) + (e[5] + e[7])) + ((e[9] + e[11]) + (e[13] + e[15]));
#pragma unroll
    for (int kt = 0; kt < 2; ++kt) {
      const unsigned A0 = packbf(e[8 * kt + 0], e[8 * kt + 1]);
      const unsigned A1 = packbf(e[8 * kt + 2], e[8 * kt + 3]);
      const unsigned B0 = packbf(e[8 * kt + 4], e[8 * kt + 5]);
      const unsigned B1 = packbf(e[8 * kt + 6], e[8 * kt + 7]);
      const uint2v r0 = __builtin_amdgcn_permlane32_swap(A0, B0, false, false);
      const uint2v r1 = __builtin_amdgcn_permlane32_swap(A1, B1, false, false);
      U128 P;
      P.u.x = r0[0];
      P.u.y = r1[0];
      P.u.z = r0[1];
      P.u.w = r1[1];
      __builtin_amdgcn_s_setprio(1);
      Oa = MFMA32(Hv[2 * kt + 0].b, P.b, Oa, 0, 0, 0);
      Ob = MFMA32(Hv[2 * kt + 1].b, P.b, Ob, 0, 0, 0);
      __builtin_amdgcn_s_setprio(0);
    }
  };
  auto body = [&](const U128* Hv, const U128& Fn, bool produce) {
    half(S0, G0, lp0v, O00, O01, Hv, Fn, produce);
    half(S1, G1, lp1v, O10, O11, Hv, Fn, produce);
  };

  // main loop: 9 iters x 3 tiles = tiles 0..26; each body followed by the
  // load of its slot's tile+3 (depth-3 in flight). Tail = tiles 27..31.
#pragma unroll 1
  for (int j = 0; j < 9; ++j) {
    body(HaA, F_B, true);               // tile 3j   -> S(3j+1)
    loadH(HaA, hp + 6144);              // H tile 3j+3
    F_A.u = *(const uint4*)(fp + 768);  // F tile 3j+3
    hp += 2048;
    fp += 256;
    body(HaB, F_C, true);               // tile 3j+1 -> S(3j+2)
    loadH(HaB, hp + 6144);              // H tile 3j+4
    F_B.u = *(const uint4*)(fp + 768);  // F tile 3j+4
    hp += 2048;
    fp += 256;
    body(HaC, F_A, true);               // tile 3j+2 -> S(3j+3)
    loadH(HaC, hp + 6144);              // H tile 3j+5
    F_C.u = *(const uint4*)(fp + 768);  // F tile 3j+5
    hp += 2048;
    fp += 256;
  }
  // tail: HaA/B/C = H(27/28/29), F_A/B/C = F(27/28/29)
  body(HaA, F_B, true);                 // tile 27 -> S(28)
  loadH(HaA, hp + 6144);                // H tile 30
  F_A.u = *(const uint4*)(fp + 768);    // F tile 30
  hp += 2048;
  fp += 256;
  body(HaB, F_C, true);                 // tile 28 -> S(29)
  loadH(HaB, hp + 6144);                // H tile 31
  F_B.u = *(const uint4*)(fp + 768);    // F tile 31
  body(HaC, F_A, true);                 // tile 29 -> S(30)
  body(HaA, F_B, true);                 // tile 30 -> S(31)
  body(HaB, F_B, false);                // tile 31 (no produce)

  // ---- epilogue: 2 phases (tile0 = O00/O01, tile1 = O10/O11) ----
  float lp0 = lp0v.x + lp0v.y;
  float lp1 = lp1v.x + lp1v.y;
  lp0 += __shfl_xor(lp0, 32, 64);
  lp1 += __shfl_xor(lp1, 32, 64);
  if (hh == 0) {
    lred[wave][ml] = lp0;
    lred[wave][32 + ml] = lp1;
  }

  const float gam = gamma[0];

  auto stash = [&](const f32x16& Oa, const f32x16& Ob) {
#pragma unroll
    for (int r = 0; r < 8; ++r) {
      const int c0 = ((2 * r) & 3) + 8 * (r >> 1) + 4 * hh;
      *(unsigned*)&Opart[wave][ml][c0] = packbf(Oa[2 * r], Oa[2 * r + 1]);
      *(unsigned*)&Opart[wave][ml][c0 + 32] = packbf(Ob[2 * r], Ob[2 * r + 1]);
    }
  };
  auto drain = [&](int p) {
    const int c = tid >> 2;
    const int m8 = (tid & 3) << 3;
    float a[8];
#pragma unroll
    for (int j = 0; j < 8; ++j) a[j] = 0.f;
#pragma unroll
    for (int w = 0; w < 4; ++w)
#pragma unroll
      for (int j = 0; j < 8; ++j) a[j] += b2f(Opart[w][m8 + j][c]);
    const f32x4 l0 = *(const f32x4*)&lsum[p * 32 + m8];
    const f32x4 l1 = *(const f32x4*)&lsum[p * 32 + m8 + 4];
    const size_t oi = (((size_t)b * 64 + c) << 12) + m0 + p * 32 + m8;
    f32x4 xo0 = *(const f32x4*)(x + oi);
    f32x4 xo1 = *(const f32x4*)(x + oi + 4);
#pragma unroll
    for (int j = 0; j < 4; ++j) {
      xo0[j] += gam / l0[j] * a[j];
      xo1[j] += gam / l1[j] * a[j + 4];
    }
    *(f32x4*)(out + oi) = xo0;
    *(f32x4*)(out + oi + 4) = xo1;
  };

  stash(O00, O01);
  __syncthreads();  // lred + phase-0 Opart visible
  if (tid < 64)
    lsum[tid] = (lred[0][tid] + lred[1][tid]) + (lred[2][tid] + lred[3][tid]);
  __syncthreads();  // lsum visible
  drain(0);
  __syncthreads();  // phase-0 reads done before overwrite
  stash(O10, O11);
  __syncthreads();  // phase-1 Opart visible
  drain(1);
}

extern "C" void kernel_launch(void* const* d_in, const int* in_sizes, int n_in,
                              void* d_out, int out_size, void* d_ws, size_t ws_size,
                              hipStream_t stream) {
  (void)in_sizes; (void)n_in; (void)out_size; (void)ws_size;
  const float* x = (const float*)d_in[0];
  const float* wq = (const float*)d_in[1];
  const float* wk = (const float*)d_in[2];
  const float* wv = (const float*)d_in[3];
  const float* gamma = (const float*)d_in[4];
  float* out = (float*)d_out;

  // workspace: f_t [8][4096][8] bf16, g_t same, h_blk [8][512][64][8] bf16
  unsigned short* f_t = (unsigned short*)d_ws;
  unsigned short* g_t = f_t + (size_t)8 * 4096 * 8;
  unsigned short* h = g_t + (size_t)8 * 4096 * 8;

  proj_kernel<<<512, 256, 0, stream>>>(x, wq, wk, wv, f_t, g_t, h);
  attn_kernel<<<512, 256, 0, stream>>>(f_t, g_t, h, x, gamma, out);
}

// Round 11
// 118.651 us; speedup vs baseline: 1.0678x; 1.0678x over previous
//
#include <hip/hip_runtime.h>
#include <hip/hip_bf16.h>

typedef __bf16 bf16x8 __attribute__((ext_vector_type(8)));
typedef float f32x4 __attribute__((ext_vector_type(4)));
typedef float f32x16 __attribute__((ext_vector_type(16)));
typedef unsigned int uint2v __attribute__((ext_vector_type(2)));

#define MFMA16 __builtin_amdgcn_mfma_f32_16x16x32_bf16
#define MFMA32 __builtin_amdgcn_mfma_f32_32x32x16_bf16

typedef const __attribute__((address_space(1))) unsigned short* gas1_t;
typedef __attribute__((address_space(3))) unsigned short* las3_t;
#define GLOAD16(g, l) \
  __builtin_amdgcn_global_load_lds((gas1_t)(g), (las3_t)(l), 16, 0, 0)
#define WAITV(N) asm volatile("s_waitcnt vmcnt(" #N ")" ::: "memory")

__device__ __forceinline__ unsigned short f2b(float f) {
  unsigned int u = __float_as_uint(f);
  u += 0x7FFFu + ((u >> 16) & 1u);
  return (unsigned short)(u >> 16);
}

__device__ __forceinline__ float b2f(unsigned short s) {
  return __uint_as_float(((unsigned)s) << 16);
}

union U128 {
  uint4 u;
  unsigned short s[8];
  bf16x8 b;
};

union BPack {
  __hip_bfloat162 h2;
  unsigned u;
};

__device__ __forceinline__ unsigned packbf(float a, float b) {
  BPack p;
  p.h2 = __float22bfloat162_rn(make_float2(a, b));
  return p.u;
}

// ---------------- projection via MFMA (unchanged, R11) ----------------
__global__ __launch_bounds__(256, 2) void proj_kernel(
    const float* __restrict__ x, const float* __restrict__ wq,
    const float* __restrict__ wk, const float* __restrict__ wv_w,
    unsigned short* __restrict__ f_t, unsigned short* __restrict__ g_t,
    unsigned short* __restrict__ h_out) {
  __shared__ unsigned short xT[64 * 64];
  __shared__ unsigned short wT[96 * 72];
  __shared__ unsigned short hT[64 * 72];

  const int tid = (int)threadIdx.x;
  const int wvp = tid >> 6;
  const int lane = tid & 63;
  const int b = (int)blockIdx.x & 7;
  const int n0 = ((int)blockIdx.x >> 3) << 6;

  {
    const float* xb = x + ((size_t)b << 18) + n0 + lane;
    const int c0 = wvp * 16;
    float xv[16];
#pragma unroll
    for (int cc = 0; cc < 16; ++cc) xv[cc] = xb[(size_t)(c0 + cc) << 12];
#pragma unroll
    for (int p = 0; p < 4; ++p) {
      const int c = c0 + 4 * p;
      uint2 d;
      d.x = packbf(xv[4 * p + 0], xv[4 * p + 1]);
      d.y = packbf(xv[4 * p + 2], xv[4 * p + 3]);
      const int g = c >> 3;
      const int idx = lane * 64 + (((g ^ (lane & 7)) << 3) | (((c >> 2) & 1) << 2));
      *(uint2*)&xT[idx] = d;
    }
  }
#pragma unroll
  for (int i = 0; i < 20; ++i) {
    const int idx = i * 256 + tid;
    const float wval = (idx < 512) ? wq[idx] * 1.44269504f
                     : (idx < 1024) ? wk[idx - 512]
                                    : wv_w[idx - 1024];
    wT[(idx >> 6) * 72 + (idx & 63)] = f2b(wval);
  }
  __syncthreads();

  const int t = lane & 15, q = lane >> 4;
  const int nloc = wvp * 16 + t;
  U128 Bf[2];
#pragma unroll
  for (int kp = 0; kp < 2; ++kp) {
    const int g = kp * 4 + q;
    Bf[kp].u = *(const uint4*)&xT[nloc * 64 + ((g ^ (nloc & 7)) << 3)];
  }
  const int nabs = n0 + nloc;

  {
    f32x4 acc = {0.f, 0.f, 0.f, 0.f};
#pragma unroll
    for (int kp = 0; kp < 2; ++kp) {
      U128 Af;
      Af.u = *(const uint4*)&wT[t * 72 + ((kp * 4 + q) << 3)];
      acc = MFMA16(Af.b, Bf[kp].b, acc, 0, 0, 0);
    }
    uint2 d;
    d.x = packbf(acc[0], acc[1]);
    d.y = packbf(acc[2], acc[3]);
    unsigned short* dst = (q & 2) ? g_t : f_t;
    *(uint2*)&dst[((size_t)((b << 12) + nabs) << 3) + ((q & 1) << 2)] = d;
  }
#pragma unroll
  for (int rt = 1; rt < 5; ++rt) {
    f32x4 acc = {0.f, 0.f, 0.f, 0.f};
#pragma unroll
    for (int kp = 0; kp < 2; ++kp) {
      U128 Af;
      Af.u = *(const uint4*)&wT[(rt * 16 + t) * 72 + ((kp * 4 + q) << 3)];
      acc = MFMA16(Af.b, Bf[kp].b, acc, 0, 0, 0);
    }
    const int cbase = (rt - 1) * 16 + 4 * q;
#pragma unroll
    for (int reg = 0; reg < 4; ++reg)
      hT[(cbase + reg) * 72 + nloc] = f2b(acc[reg]);
  }
  __syncthreads();

  {
    const int hc = tid & 63;
    const int hw = tid >> 6;
    const uint4 v0 = *(const uint4*)&hT[hc * 72 + hw * 16];
    const uint4 v1 = *(const uint4*)&hT[hc * 72 + hw * 16 + 8];
    const size_t hbase =
        ((size_t)b << 18) + ((size_t)((n0 + hw * 16) >> 3) << 9) + (hc << 3);
    *(uint4*)&h_out[hbase] = v0;
    *(uint4*)&h_out[hbase + 512] = v1;
  }
}

// ---------------- flash attention ------------------------------------------
// R18 = R16 compute (grid 512, 256 thr, 4 indep waves, m64/ILP2, in-place S
// pipeline) + LDS-STAGED H/F (global_load_lds, depth-3, counted vmcnt) and
// ALL setprio removed (m190: setprio hurts symmetric-wave kernels; our 4
// waves are symmetric).
// Register prefetch is impossible (R9/R13/R15/R17 all spilled: unified RF,
// R12's working set is at the edge). LDS slots cost 0 VGPRs: each wave owns
// 3 slots x 5 KB (4 KB H + 1 KB F). Body k: WAITV(5) (tile k,k+1 staged;
// only stage k+2 outstanding -> never drain to 0, T4), ds_read H(k) frags +
// F(k+1) frag, lgkmcnt(0)+sched_barrier fence (rule #18), then stage tile
// k+3 into the just-freed slot (5x global_load_lds, 16 B/lane, linear copy).
// Loads are ~2 bodies (~1200 cy) in flight vs L2 latency ~200-500 cy.
// LDS: 60 KB staging (per-wave private -> NO barriers in main loop) +
// epilogue Opart aliased onto staging region (barrier before stash).
__global__ __launch_bounds__(256, 2) void attn_kernel(
    const unsigned short* __restrict__ f_t, const unsigned short* __restrict__ g_t,
    const unsigned short* __restrict__ h, const float* __restrict__ x,
    const float* __restrict__ gamma, float* __restrict__ out) {
  __shared__ unsigned short SMEM[4 * 3 * 2560];  // 60 KB staging / Opart alias
  __shared__ float lred[4][64];
  __shared__ float lsum[64];

  const int tid = (int)threadIdx.x;
  const int wave = tid >> 6;
  const int lane = tid & 63;
  const int ml = lane & 31;
  const int hh = lane >> 5;

  const int b = (int)blockIdx.x & 7;
  const int m0 = ((int)blockIdx.x >> 3) << 6;  // m64 tile base

  const unsigned short* fb = f_t + ((size_t)b << 15);
  const unsigned short* hb = h + ((size_t)b << 18);  // blocked layout

  U128 G0, G1;
  G0.u = make_uint4(0u, 0u, 0u, 0u);
  G1.u = make_uint4(0u, 0u, 0u, 0u);
  if (hh == 0) {
    G0.u = *(const uint4*)(g_t + ((size_t)((b << 12) + m0 + ml) << 3));
    G1.u = *(const uint4*)(g_t + ((size_t)((b << 12) + m0 + 32 + ml) << 3));
  }

  f32x16 O00 = {}, O01 = {}, O10 = {}, O11 = {};
  float2 lp0v = make_float2(0.f, 0.f), lp1v = make_float2(0.f, 0.f);
  const f32x16 ZC = {};

  const int nbase = wave << 10;     // n-quarter per wave (1024 n = 32 tiles)
  const int wbase = wave * 7680;    // per-wave LDS region (entries)

  // tile t: H = gH0 + t*2048 (4 KB), F = gF0 + t*256 (512 B, dup to 1 KB)
  const unsigned short* gH0 = hb + ((size_t)nbase << 6);
  const unsigned short* gF0 = fb + ((size_t)nbase << 3);

  f32x16 S0, S1;

  // stage tile (5 x global_load_lds): H 4 KB linear + F duplicated halves
  auto stageT = [&](int slot, const unsigned short* gh, const unsigned short* gf) {
    unsigned short* l = &SMEM[wbase + slot * 2560];
#pragma unroll
    for (int i = 0; i < 4; ++i)
      GLOAD16(gh + i * 512 + lane * 8, l + i * 512);
    GLOAD16(gf + (lane & 31) * 8, l + 2048);
  };

  // half: exps consume S; optional produce S <- MFMA(Fv,G) in place; pack
  // + permlane32_swap; PV MFMAs. (no setprio — m190)
  auto half = [&](f32x16& S, const U128& G, float2& lp, f32x16& Oa, f32x16& Ob,
                  const U128& Hv0, const U128& Hv1, const U128& Hv2,
                  const U128& Hv3, const U128& Fv, bool produce) {
    float e[16];
#pragma unroll
    for (int r = 0; r < 16; ++r) e[r] = __builtin_amdgcn_exp2f(S[r]);
    if (produce) S = MFMA32(Fv.b, G.b, ZC, 0, 0, 0);
    lp.x += ((e[0] + e[2]) + (e[4] + e[6])) + ((e[8] + e[10]) + (e[12] + e[14]));
    lp.y += ((e[1] + e[3]) + (e[5] + e[7])) + ((e[9] + e[11]) + (e[13] + e[15]));
#pragma unroll
    for (int kt = 0; kt < 2; ++kt) {
      const unsigned A0 = packbf(e[8 * kt + 0], e[8 * kt + 1]);
      const unsigned A1 = packbf(e[8 * kt + 2], e[8 * kt + 3]);
      const unsigned B0 = packbf(e[8 * kt + 4], e[8 * kt + 5]);
      const unsigned B1 = packbf(e[8 * kt + 6], e[8 * kt + 7]);
      const uint2v r0 = __builtin_amdgcn_permlane32_swap(A0, B0, false, false);
      const uint2v r1 = __builtin_amdgcn_permlane32_swap(A1, B1, false, false);
      U128 P;
      P.u.x = r0[0];
      P.u.y = r1[0];
      P.u.z = r0[1];
      P.u.w = r1[1];
      if (kt == 0) {
        Oa = MFMA32(Hv0.b, P.b, Oa, 0, 0, 0);
        Ob = MFMA32(Hv1.b, P.b, Ob, 0, 0, 0);
      } else {
        Oa = MFMA32(Hv2.b, P.b, Oa, 0, 0, 0);
        Ob = MFMA32(Hv3.b, P.b, Ob, 0, 0, 0);
      }
    }
  };

  // body k: ds_read H(k) from slot sH + F(k+1) from slot sF; fence; stage
  // tile k+3 into sH (if gh != nullptr); compute both halves.
  auto bodyk = [&](int sH, int sF, const unsigned short* gh,
                   const unsigned short* gf, bool produce) {
    const unsigned short* pH = &SMEM[wbase + sH * 2560];
    const unsigned short* pF = &SMEM[wbase + sF * 2560 + 2048];
    const int ho = hh * 512 + ml * 8;
    U128 Hv0, Hv1, Hv2, Hv3, Fv;
    Hv0.u = *(const uint4*)&pH[ho];
    Hv1.u = *(const uint4*)&pH[ho + 256];
    Hv2.u = *(const uint4*)&pH[ho + 1024];
    Hv3.u = *(const uint4*)&pH[ho + 1280];
    Fv.u = *(const uint4*)&pF[hh * 256 + ml * 8];
    asm volatile("s_waitcnt lgkmcnt(0)" ::: "memory");
    __builtin_amdgcn_sched_barrier(0);
    if (gh) stageT(sH, gh, gf);
    half(S0, G0, lp0v, O00, O01, Hv0, Hv1, Hv2, Hv3, Fv, produce);
    half(S1, G1, lp1v, O10, O11, Hv0, Hv1, Hv2, Hv3, Fv, produce);
  };

  // prologue: stage tiles 0,1,2; wait stage0 done; S = scores(tile 0)
  stageT(0, gH0, gF0);
  stageT(1, gH0 + 2048, gF0 + 256);
  stageT(2, gH0 + 4096, gF0 + 512);
  WAITV(10);
  {
    U128 F0v;
    F0v.u = *(const uint4*)&SMEM[wbase + 2048 + hh * 256 + ml * 8];
    S0 = MFMA32(F0v.b, G0.b, ZC, 0, 0, 0);
    S1 = MFMA32(F0v.b, G1.b, ZC, 0, 0, 0);
  }

  // main loop: tiles 0..26 (9 x 3, slots rotate 0,1,2); stage k+3 each body.
  const unsigned short* gHs = gH0 + 3 * 2048;
  const unsigned short* gFs = gF0 + 3 * 256;
#pragma unroll 1
  for (int j = 0; j < 9; ++j) {
    WAITV(5);
    bodyk(0, 1, gHs, gFs, true);
    WAITV(5);
    bodyk(1, 2, gHs + 2048, gFs + 256, true);
    WAITV(5);
    bodyk(2, 0, gHs + 4096, gFs + 512, true);
    gHs += 6144;
    gFs += 768;
  }
  // tail: tiles 27..31 (k%3 = 0,1,2,0,1); stages for tiles 30,31 only.
  WAITV(5);
  bodyk(0, 1, gHs, gFs, true);              // k=27, stage 30
  WAITV(5);
  bodyk(1, 2, gHs + 2048, gFs + 256, true); // k=28, stage 31
  WAITV(5);
  bodyk(2, 0, nullptr, nullptr, true);      // k=29
  WAITV(0);
  bodyk(0, 1, nullptr, nullptr, true);      // k=30 (needs F(31))
  WAITV(0);
  bodyk(1, 2, nullptr, nullptr, false);     // k=31 (no produce)

  // ---- epilogue: 2 phases; Opart aliases the staging LDS ----
  float lp0 = lp0v.x + lp0v.y;
  float lp1 = lp1v.x + lp1v.y;
  lp0 += __shfl_xor(lp0, 32, 64);
  lp1 += __shfl_xor(lp1, 32, 64);
  if (hh == 0) {
    lred[wave][ml] = lp0;
    lred[wave][32 + ml] = lp1;
  }

  unsigned short (*Opart)[32][66] = (unsigned short (*)[32][66])SMEM;
  const float gam = gamma[0];

  auto stash = [&](const f32x16& Oa, const f32x16& Ob) {
#pragma unroll
    for (int r = 0; r < 8; ++r) {
      const int c0 = ((2 * r) & 3) + 8 * (r >> 1) + 4 * hh;
      *(unsigned*)&Opart[wave][ml][c0] = packbf(Oa[2 * r], Oa[2 * r + 1]);
      *(unsigned*)&Opart[wave][ml][c0 + 32] = packbf(Ob[2 * r], Ob[2 * r + 1]);
    }
  };
  auto drain = [&](int p) {
    const int c = tid >> 2;
    const int m8 = (tid & 3) << 3;
    float a[8];
#pragma unroll
    for (int j = 0; j < 8; ++j) a[j] = 0.f;
#pragma unroll
    for (int w = 0; w < 4; ++w)
#pragma unroll
      for (int j = 0; j < 8; ++j) a[j] += b2f(Opart[w][m8 + j][c]);
    const f32x4 l0 = *(const f32x4*)&lsum[p * 32 + m8];
    const f32x4 l1 = *(const f32x4*)&lsum[p * 32 + m8 + 4];
    const size_t oi = (((size_t)b * 64 + c) << 12) + m0 + p * 32 + m8;
    f32x4 xo0 = *(const f32x4*)(x + oi);
    f32x4 xo1 = *(const f32x4*)(x + oi + 4);
#pragma unroll
    for (int j = 0; j < 4; ++j) {
      xo0[j] += gam / l0[j] * a[j];
      xo1[j] += gam / l1[j] * a[j + 4];
    }
    *(f32x4*)(out + oi) = xo0;
    *(f32x4*)(out + oi + 4) = xo1;
  };

  __syncthreads();  // all waves done with staged LDS before Opart alias reuse
  stash(O00, O01);
  __syncthreads();  // lred + phase-0 Opart visible
  if (tid < 64)
    lsum[tid] = (lred[0][tid] + lred[1][tid]) + (lred[2][tid] + lred[3][tid]);
  __syncthreads();  // lsum visible
  drain(0);
  __syncthreads();  // phase-0 reads done before overwrite
  stash(O10, O11);
  __syncthreads();  // phase-1 Opart visible
  drain(1);
}

extern "C" void kernel_launch(void* const* d_in, const int* in_sizes, int n_in,
                              void* d_out, int out_size, void* d_ws, size_t ws_size,
                              hipStream_t stream) {
  (void)in_sizes; (void)n_in; (void)out_size; (void)ws_size;
  const float* x = (const float*)d_in[0];
  const float* wq = (const float*)d_in[1];
  const float* wk = (const float*)d_in[2];
  const float* wv = (const float*)d_in[3];
  const float* gamma = (const float*)d_in[4];
  float* out = (float*)d_out;

  // workspace: f_t [8][4096][8] bf16, g_t same, h_blk [8][512][64][8] bf16
  unsigned short* f_t = (unsigned short*)d_ws;
  unsigned short* g_t = f_t + (size_t)8 * 4096 * 8;
  unsigned short* h = g_t + (size_t)8 * 4096 * 8;

  proj_kernel<<<512, 256, 0, stream>>>(x, wq, wk, wv, f_t, g_t, h);
  attn_kernel<<<512, 256, 0, stream>>>(f_t, g_t, h, x, gamma, out);
}

// Round 12
// 101.169 us; speedup vs baseline: 1.2524x; 1.1728x over previous
//
#include <hip/hip_runtime.h>
#include <hip/hip_bf16.h>

typedef __bf16 bf16x8 __attribute__((ext_vector_type(8)));
typedef float f32x4 __attribute__((ext_vector_type(4)));
typedef float f32x16 __attribute__((ext_vector_type(16)));
typedef unsigned int uint2v __attribute__((ext_vector_type(2)));

#define MFMA16 __builtin_amdgcn_mfma_f32_16x16x32_bf16
#define MFMA32 __builtin_amdgcn_mfma_f32_32x32x16_bf16

__device__ __forceinline__ unsigned short f2b(float f) {
  unsigned int u = __float_as_uint(f);
  u += 0x7FFFu + ((u >> 16) & 1u);
  return (unsigned short)(u >> 16);
}

__device__ __forceinline__ float b2f(unsigned short s) {
  return __uint_as_float(((unsigned)s) << 16);
}

union U128 {
  uint4 u;
  unsigned short s[8];
  bf16x8 b;
};

union BPack {
  __hip_bfloat162 h2;
  unsigned u;
};

__device__ __forceinline__ unsigned packbf(float a, float b) {
  BPack p;
  p.h2 = __float22bfloat162_rn(make_float2(a, b));
  return p.u;
}

// ---------------- projection via MFMA ----------------
// grid 512 = (b = blk&7, n0 = 64-tile). block 256 (4 waves).
// Y[96 pad][4096] = W[96x64] X[64x4096] per batch, bf16 MFMA 16x16x32.
// wq rows pre-scaled by log2(e) so attention uses native exp2.
// h stored BLOCKED: h_blk[b][n>>3][c][n&7].
// R11: packed stores (f/g one 8 B store; h bounced via LDS, 2x16 B stores).
__global__ __launch_bounds__(256, 2) void proj_kernel(
    const float* __restrict__ x, const float* __restrict__ wq,
    const float* __restrict__ wk, const float* __restrict__ wv_w,
    unsigned short* __restrict__ f_t, unsigned short* __restrict__ g_t,
    unsigned short* __restrict__ h_out) {
  __shared__ unsigned short xT[64 * 64];
  __shared__ unsigned short wT[96 * 72];
  __shared__ unsigned short hT[64 * 72];  // [c][n], pad 72 (16B-aligned rows)

  const int tid = (int)threadIdx.x;
  const int wvp = tid >> 6;
  const int lane = tid & 63;
  const int b = (int)blockIdx.x & 7;
  const int n0 = ((int)blockIdx.x >> 3) << 6;

  // ---- stage xT: thread loads 16 c's for n=lane, packs, swizzled write ----
  {
    const float* xb = x + ((size_t)b << 18) + n0 + lane;
    const int c0 = wvp * 16;
    float xv[16];
#pragma unroll
    for (int cc = 0; cc < 16; ++cc) xv[cc] = xb[(size_t)(c0 + cc) << 12];
#pragma unroll
    for (int p = 0; p < 4; ++p) {
      const int c = c0 + 4 * p;
      uint2 d;
      d.x = packbf(xv[4 * p + 0], xv[4 * p + 1]);
      d.y = packbf(xv[4 * p + 2], xv[4 * p + 3]);
      const int g = c >> 3;
      const int idx = lane * 64 + (((g ^ (lane & 7)) << 3) | (((c >> 2) & 1) << 2));
      *(uint2*)&xT[idx] = d;
    }
  }
  // ---- stage wT (80 rows of 64, bf16); wq scaled by log2(e) ----
#pragma unroll
  for (int i = 0; i < 20; ++i) {
    const int idx = i * 256 + tid;
    const float wval = (idx < 512) ? wq[idx] * 1.44269504f
                     : (idx < 1024) ? wk[idx - 512]
                                    : wv_w[idx - 1024];
    wT[(idx >> 6) * 72 + (idx & 63)] = f2b(wval);
  }
  __syncthreads();

  // ---- compute ----
  const int t = lane & 15, q = lane >> 4;
  const int nloc = wvp * 16 + t;
  U128 Bf[2];
#pragma unroll
  for (int kp = 0; kp < 2; ++kp) {
    const int g = kp * 4 + q;
    Bf[kp].u = *(const uint4*)&xT[nloc * 64 + ((g ^ (nloc & 7)) << 3)];
  }
  const int nabs = n0 + nloc;

  // rt = 0: f (r0-7) / g (r8-15): one packed 8 B store per thread.
  {
    f32x4 acc = {0.f, 0.f, 0.f, 0.f};
#pragma unroll
    for (int kp = 0; kp < 2; ++kp) {
      U128 Af;
      Af.u = *(const uint4*)&wT[t * 72 + ((kp * 4 + q) << 3)];
      acc = MFMA16(Af.b, Bf[kp].b, acc, 0, 0, 0);
    }
    uint2 d;
    d.x = packbf(acc[0], acc[1]);
    d.y = packbf(acc[2], acc[3]);
    unsigned short* dst = (q & 2) ? g_t : f_t;
    *(uint2*)&dst[((size_t)((b << 12) + nabs) << 3) + ((q & 1) << 2)] = d;
  }
  // rt = 1..4: h rows -> LDS, transposed packed readback below.
#pragma unroll
  for (int rt = 1; rt < 5; ++rt) {
    f32x4 acc = {0.f, 0.f, 0.f, 0.f};
#pragma unroll
    for (int kp = 0; kp < 2; ++kp) {
      U128 Af;
      Af.u = *(const uint4*)&wT[(rt * 16 + t) * 72 + ((kp * 4 + q) << 3)];
      acc = MFMA16(Af.b, Bf[kp].b, acc, 0, 0, 0);
    }
    const int cbase = (rt - 1) * 16 + 4 * q;
#pragma unroll
    for (int reg = 0; reg < 4; ++reg)
      hT[(cbase + reg) * 72 + nloc] = f2b(acc[reg]);
  }
  __syncthreads();

  // packed h store: thread owns row c = tid&63, n-quarter = tid>>6.
  {
    const int hc = tid & 63;
    const int hw = tid >> 6;
    const uint4 v0 = *(const uint4*)&hT[hc * 72 + hw * 16];
    const uint4 v1 = *(const uint4*)&hT[hc * 72 + hw * 16 + 8];
    const size_t hbase =
        ((size_t)b << 18) + ((size_t)((n0 + hw * 16) >> 3) << 9) + (hc << 3);
    *(uint4*)&h_out[hbase] = v0;
    *(uint4*)&h_out[hbase + 512] = v1;
  }
}

// ---------------- flash attention ------------------------------------------
// R19 = R16 (best-known: grid 512, 256 thr, 4 indep waves, m64/ILP2,
// H ping-pong, in-place S pipeline, imm-foldable offsets, float2 lp)
// with ALL s_setprio REMOVED — the one variable confounded since R9.
// Priors conflict: m191 (+4-7%, independent-wave attn) vs m190 (-1.5%,
// symmetric waves). This is the clean A/B. Everything else byte-identical
// to R16 (102.3 us).
// Structural attacks on the ~42 us attn floor are exhausted: register
// prefetch spills (R9/R13/R15/R17 — unified RF, working set at the edge),
// LDS staging is slower (R18: +ds_read/fence on critical path + spill),
// more waves hurt (R14), ILP/occupancy swap neutral (R12), score-MFMA
// pipelining neutral (R10), VALU diet neutral (R16).
__global__ __launch_bounds__(256, 2) void attn_kernel(
    const unsigned short* __restrict__ f_t, const unsigned short* __restrict__ g_t,
    const unsigned short* __restrict__ h, const float* __restrict__ x,
    const float* __restrict__ gamma, float* __restrict__ out) {
  __shared__ unsigned short Opart[4][16][66];  // [wave][m-slice][c], 8.45 KB
  __shared__ float lred[4][64];
  __shared__ float lsum[64];

  const int tid = (int)threadIdx.x;
  const int wave = tid >> 6;
  const int lane = tid & 63;
  const int ml = lane & 31;
  const int hh = lane >> 5;

  const int b = (int)blockIdx.x & 7;
  const int m0 = ((int)blockIdx.x >> 3) << 6;  // m64 tile base

  const unsigned short* fb = f_t + ((size_t)b << 15);
  const unsigned short* hb = h + ((size_t)b << 18);  // blocked layout

  U128 G0, G1;
  G0.u = make_uint4(0u, 0u, 0u, 0u);
  G1.u = make_uint4(0u, 0u, 0u, 0u);
  if (hh == 0) {
    G0.u = *(const uint4*)(g_t + ((size_t)((b << 12) + m0 + ml) << 3));
    G1.u = *(const uint4*)(g_t + ((size_t)((b << 12) + m0 + 32 + ml) << 3));
  }

  f32x16 O00 = {}, O01 = {}, O10 = {}, O11 = {};
  float2 lp0v = make_float2(0.f, 0.f), lp1v = make_float2(0.f, 0.f);
  const f32x16 ZC = {};

  const int nbase = wave << 10;  // n-quarter per wave (1024 n = 32 tiles)

  const unsigned short* fp = fb + ((size_t)(nbase + ml) << 3);
  const unsigned short* hp = hb + ((nbase >> 3) << 9) + (hh << 9) + (ml << 3);

  // fragment slots: F ping-pong (2), H ping-pong (2x4), TWO in-place S
  U128 F0, F1, Ha_e[4], Ha_o[4];
  f32x16 S0, S1;

  // prologue: F tiles 0,1; H tile 0; S0/S1 = scores(tile 0)
  F0.u = *(const uint4*)(fp);
  F1.u = *(const uint4*)(fp + 256);
  Ha_e[0].u = *(const uint4*)(hp);
  Ha_e[1].u = *(const uint4*)(hp + 256);
  Ha_e[2].u = *(const uint4*)(hp + 1024);
  Ha_e[3].u = *(const uint4*)(hp + 1280);
  S0 = MFMA32(F0.b, G0.b, ZC, 0, 0, 0);
  S1 = MFMA32(F0.b, G1.b, ZC, 0, 0, 0);

  // half: exps consume S (tile k, this G); if produce, S <- scores(k+1)
  // in place; pack + PV into this m-tile's O pair using shared H fragments.
  auto half = [&](f32x16& S, const U128& G, float2& lp, f32x16& Oa, f32x16& Ob,
                  const U128* Hv, const U128& Fn, bool produce) {
    float e[16];
#pragma unroll
    for (int r = 0; r < 16; ++r) e[r] = __builtin_amdgcn_exp2f(S[r]);
    if (produce) S = MFMA32(Fn.b, G.b, ZC, 0, 0, 0);
    // denominator partial: even/odd split -> paired adds, depth-3 trees
    lp.x += ((e[0] + e[2]) + (e[4] + e[6])) + ((e[8] + e[10]) + (e[12] + e[14]));
    lp.y += ((e[1] + e[3]) + (e[5] + e[7])) + ((e[9] + e[11]) + (e[13] + e[15]));
#pragma unroll
    for (int kt = 0; kt < 2; ++kt) {
      const unsigned A0 = packbf(e[8 * kt + 0], e[8 * kt + 1]);
      const unsigned A1 = packbf(e[8 * kt + 2], e[8 * kt + 3]);
      const unsigned B0 = packbf(e[8 * kt + 4], e[8 * kt + 5]);
      const unsigned B1 = packbf(e[8 * kt + 6], e[8 * kt + 7]);
      const uint2v r0 = __builtin_amdgcn_permlane32_swap(A0, B0, false, false);
      const uint2v r1 = __builtin_amdgcn_permlane32_swap(A1, B1, false, false);
      U128 P;
      P.u.x = r0[0];
      P.u.y = r1[0];
      P.u.z = r0[1];
      P.u.w = r1[1];
      Oa = MFMA32(Hv[2 * kt + 0].b, P.b, Oa, 0, 0, 0);
      Ob = MFMA32(Hv[2 * kt + 1].b, P.b, Ob, 0, 0, 0);
    }
  };
  auto body = [&](const U128* Hv, const U128& Fn, bool produce) {
    half(S0, G0, lp0v, O00, O01, Hv, Fn, produce);
    half(S1, G1, lp1v, O10, O11, Hv, Fn, produce);
  };

  // main loop: tiles 2j, 2j+1 for j=0..14; tiles 30,31 peeled.
  // hp bumped MID-iteration: all H-load offsets stay <= 6656 B (imm-foldable).
#pragma unroll 1
  for (int j = 0; j < 15; ++j) {
    Ha_o[0].u = *(const uint4*)(hp + 2048);   // H tile 2j+1 (4096 B)
    Ha_o[1].u = *(const uint4*)(hp + 2304);   // (4608 B)
    Ha_o[2].u = *(const uint4*)(hp + 3072);   // (6144 B)
    Ha_o[3].u = *(const uint4*)(hp + 3328);   // (6656 B)
    F0.u = *(const uint4*)(fp + 512);         // F tile 2j+2 (1024 B)
    body(Ha_e, F1, true);                     // tile 2j, S <- scores(2j+1)
    hp += 4096;                               // -> base of tile 2j+2
    Ha_e[0].u = *(const uint4*)(hp);          // H tile 2j+2 (0 B)
    Ha_e[1].u = *(const uint4*)(hp + 256);    // (512 B)
    Ha_e[2].u = *(const uint4*)(hp + 1024);   // (2048 B)
    Ha_e[3].u = *(const uint4*)(hp + 1280);   // (2560 B)
    F1.u = *(const uint4*)(fp + 768);         // F tile 2j+3 (1536 B)
    body(Ha_o, F0, true);                     // tile 2j+1, S <- scores(2j+2)
    fp += 512;
  }
  // tail: hp = base of tile 30; Ha_e holds H(30), F1 holds F(31)
  Ha_o[0].u = *(const uint4*)(hp + 2048);     // H tile 31
  Ha_o[1].u = *(const uint4*)(hp + 2304);
  Ha_o[2].u = *(const uint4*)(hp + 3072);
  Ha_o[3].u = *(const uint4*)(hp + 3328);
  body(Ha_e, F1, true);                       // tile 30, S <- scores(31)
  body(Ha_o, F1, false);                      // tile 31 (no produce)

  // ---- epilogue: 4 m16-phases through one Opart buffer ----
  float lp0 = lp0v.x + lp0v.y;
  float lp1 = lp1v.x + lp1v.y;
  lp0 += __shfl_xor(lp0, 32, 64);
  lp1 += __shfl_xor(lp1, 32, 64);
  if (hh == 0) {
    lred[wave][ml] = lp0;
    lred[wave][32 + ml] = lp1;
  }

  const float gam = gamma[0];

  // stash m-slice p (16 rows): p<2 -> tile0 (O00/O01), else tile1 (O10/O11)
  auto stash = [&](int p, const f32x16& Oa, const f32x16& Ob) {
    if ((ml >> 4) == (p & 1)) {
      const int mi = ml & 15;
#pragma unroll
      for (int r = 0; r < 8; ++r) {
        const int c0 = ((2 * r) & 3) + 8 * (r >> 1) + 4 * hh;
        *(unsigned*)&Opart[wave][mi][c0] = packbf(Oa[2 * r], Oa[2 * r + 1]);
        *(unsigned*)&Opart[wave][mi][c0 + 32] = packbf(Ob[2 * r], Ob[2 * r + 1]);
      }
    }
  };
  auto drain = [&](int p) {
    const int c = tid >> 2;
    const int m4 = (tid & 3) << 2;
    float a0 = 0.f, a1 = 0.f, a2 = 0.f, a3 = 0.f;
#pragma unroll
    for (int w = 0; w < 4; ++w) {
      a0 += b2f(Opart[w][m4 + 0][c]);
      a1 += b2f(Opart[w][m4 + 1][c]);
      a2 += b2f(Opart[w][m4 + 2][c]);
      a3 += b2f(Opart[w][m4 + 3][c]);
    }
    const f32x4 l = *(const f32x4*)&lsum[p * 16 + m4];
    const size_t oi = (((size_t)b * 64 + c) << 12) + m0 + p * 16 + m4;
    f32x4 xo = *(const f32x4*)(x + oi);
    xo[0] += gam / l[0] * a0;
    xo[1] += gam / l[1] * a1;
    xo[2] += gam / l[2] * a2;
    xo[3] += gam / l[3] * a3;
    *(f32x4*)(out + oi) = xo;
  };

  stash(0, O00, O01);
  __syncthreads();  // lred + phase-0 Opart visible
  if (tid < 64)
    lsum[tid] = (lred[0][tid] + lred[1][tid]) + (lred[2][tid] + lred[3][tid]);
  __syncthreads();  // lsum visible
  drain(0);
  __syncthreads();
  stash(1, O00, O01);
  __syncthreads();
  drain(1);
  __syncthreads();
  stash(2, O10, O11);
  __syncthreads();
  drain(2);
  __syncthreads();
  stash(3, O10, O11);
  __syncthreads();
  drain(3);
}

extern "C" void kernel_launch(void* const* d_in, const int* in_sizes, int n_in,
                              void* d_out, int out_size, void* d_ws, size_t ws_size,
                              hipStream_t stream) {
  (void)in_sizes; (void)n_in; (void)out_size; (void)ws_size;
  const float* x = (const float*)d_in[0];
  const float* wq = (const float*)d_in[1];
  const float* wk = (const float*)d_in[2];
  const float* wv = (const float*)d_in[3];
  const float* gamma = (const float*)d_in[4];
  float* out = (float*)d_out;

  // workspace: f_t [8][4096][8] bf16, g_t same, h_blk [8][512][64][8] bf16
  unsigned short* f_t = (unsigned short*)d_ws;
  unsigned short* g_t = f_t + (size_t)8 * 4096 * 8;
  unsigned short* h = g_t + (size_t)8 * 4096 * 8;

  proj_kernel<<<512, 256, 0, stream>>>(x, wq, wk, wv, f_t, g_t, h);
  attn_kernel<<<512, 256, 0, stream>>>(f_t, g_t, h, x, gamma, out);
}